// Round 3
// baseline (1323.063 us; speedup 1.0000x reference)
//
#include <hip/hip_runtime.h>

// ---------------------------------------------------------------------------
// ReconGNN: out = conv(relu(conv(x@W1^T)+b1) @ W2^T) + b2
// conv = symmetric-normalized GCN aggregation over edge_index.
// R3: per-node CSR abolished (k_fill's 4B random scatter cost 105MB of
// write-allocate HBM traffic / 135us). Edges are bucketed into bins of 256
// destination nodes with coalesced run writes; each conv block accumulates
// its bin's 256xD tile in LDS via ds_add_f32 and writes coalesced output.
// Pipeline: memset(gbincnt) -> detect -> binfill -> bindeg(dis) ->
//           gemm1 -> binconv1(relu+b1) -> gemm2 -> binconv2(+b2)
// ---------------------------------------------------------------------------

// ---- edge dtype detection: int64 edges read as int32 have all-zero odd words
__global__ void k_detect(const int* __restrict__ ed, int* __restrict__ flag, int nwords) {
  __shared__ int any;
  if (threadIdx.x == 0) any = 0;
  __syncthreads();
  #pragma unroll
  for (int u = 0; u < 8; ++u) {
    int idx = 2 * (threadIdx.x * 8 + u) + 1;   // odd words 1..4095
    if (idx < nwords && ed[idx] != 0) any = 1; // benign race
  }
  __syncthreads();
  if (threadIdx.x == 0) *flag = any ? 0 : 1;   // 1 => int64 layout
}

// ---- bucket edges by destination bin (c>>8), coalesced run writes ----
// record = r | (c&255)<<17   (N <= 131072)
__global__ void k_binfill(const int* __restrict__ ed, const int* __restrict__ flag,
                          int* __restrict__ gbincnt, unsigned* __restrict__ binbuf,
                          int E, int cap) {
  __shared__ int hist[512];
  __shared__ int cursor[512];
  int t = threadIdx.x;
  hist[t] = 0; hist[t + 256] = 0;
  __syncthreads();
  const int is64 = *flag;
  const int base = blockIdx.x * 8192;
  const int nE = min(8192, E - base);
  // phase 1: block-local bin histogram
  for (int j = t; j < nE; j += 256) {
    int e = base + j;
    int c = is64 ? ed[2 * (E + e)] : ed[E + e];
    atomicAdd(&hist[c >> 8], 1);
  }
  __syncthreads();
  // phase 2: reserve a contiguous global run per bin
  for (int b = t; b < 512; b += 256) {
    int h = hist[b];
    cursor[b] = h ? atomicAdd(&gbincnt[b], h) : 0;
  }
  __syncthreads();
  // phase 3: scatter into the reserved runs (order within bin irrelevant)
  for (int j = t; j < nE; j += 256) {
    int e = base + j;
    int r = is64 ? ed[2 * e] : ed[e];
    int c = is64 ? ed[2 * (E + e)] : ed[E + e];
    int bin = c >> 8;
    int pos = atomicAdd(&cursor[bin], 1);
    if (pos < cap)
      binbuf[(size_t)bin * cap + pos] = (unsigned)r | ((unsigned)(c & 255) << 17);
  }
}

// ---- per-bin degree -> dis = rsqrt(deg) (replaces global hist + scans) ----
__global__ void k_bindeg(const unsigned* __restrict__ binbuf, const int* __restrict__ gbincnt,
                         float* __restrict__ dis, int N, int cap) {
  __shared__ int cnt[256];
  int t = threadIdx.x, b = blockIdx.x;
  cnt[t] = 0;
  __syncthreads();
  int n = min(gbincnt[b], cap);
  const unsigned* buf = binbuf + (size_t)b * cap;
  for (int j = t; j < n; j += 256) atomicAdd(&cnt[buf[j] >> 17], 1);
  __syncthreads();
  int node = b * 256 + t;
  if (node < N) {
    int c = cnt[t];
    dis[node] = (c > 0) ? rsqrtf((float)c) : 0.f;
  }
}

// ---- GEMM: Y[N][MREAL] = X[N][KFULL] @ W[MREAL][KFULL]^T (R2, unchanged) ----
template<int KFULL, int MREAL>
__launch_bounds__(128)
__global__ void k_gemm(const float* __restrict__ X, const float* __restrict__ W,
                       float* __restrict__ Y, int N) {
  constexpr int BM = 128, BK = 32;
  __shared__ float xs[BM * BK];
  __shared__ float wt[BK * 64];
  const int tid = threadIdx.x;
  const int tr = tid >> 3;
  const int tc = tid & 7;
  const int row0 = blockIdx.x * BM;
  const int c0 = tc * 8;

  float4 acc[8][2];
  #pragma unroll
  for (int i = 0; i < 8; ++i) {
    acc[i][0] = make_float4(0.f, 0.f, 0.f, 0.f);
    acc[i][1] = make_float4(0.f, 0.f, 0.f, 0.f);
  }

  #pragma unroll 1
  for (int kt = 0; kt < KFULL / BK; ++kt) {
    if (kt) __syncthreads();
    #pragma unroll
    for (int j = 0; j < 8; ++j) {
      int q = tid + 128 * j;
      int r = q >> 3, kq = q & 7;
      float4 v = make_float4(0.f, 0.f, 0.f, 0.f);
      int row = row0 + r;
      if (row < N) v = *(const float4*)&X[(size_t)row * KFULL + kt * BK + kq * 4];
      *(float4*)&xs[r * 32 + ((kq ^ ((r >> 3) & 7)) << 2)] = v;
    }
    #pragma unroll
    for (int j = 0; j < 4; ++j) {
      int q = tid + 128 * j;
      int c = q >> 3, kq = q & 7;
      float4 v = make_float4(0.f, 0.f, 0.f, 0.f);
      if (c < MREAL) v = *(const float4*)&W[(size_t)c * KFULL + kt * BK + kq * 4];
      wt[(kq * 4 + 0) * 64 + c] = v.x;
      wt[(kq * 4 + 1) * 64 + c] = v.y;
      wt[(kq * 4 + 2) * 64 + c] = v.z;
      wt[(kq * 4 + 3) * 64 + c] = v.w;
    }
    __syncthreads();

    #pragma unroll 2
    for (int kq = 0; kq < 8; ++kq) {
      float4 xr[8];
      #pragma unroll
      for (int i = 0; i < 8; ++i)
        xr[i] = *(const float4*)&xs[(tr * 8 + i) * 32 + ((kq ^ (tr & 7)) << 2)];
      #pragma unroll
      for (int kk = 0; kk < 4; ++kk) {
        int k = kq * 4 + kk;
        float4 w0 = *(const float4*)&wt[k * 64 + c0];
        float4 w1 = *(const float4*)&wt[k * 64 + c0 + 4];
        #pragma unroll
        for (int i = 0; i < 8; ++i) {
          float xv = ((const float*)&xr[i])[kk];
          acc[i][0].x = fmaf(xv, w0.x, acc[i][0].x);
          acc[i][0].y = fmaf(xv, w0.y, acc[i][0].y);
          acc[i][0].z = fmaf(xv, w0.z, acc[i][0].z);
          acc[i][0].w = fmaf(xv, w0.w, acc[i][0].w);
          acc[i][1].x = fmaf(xv, w1.x, acc[i][1].x);
          acc[i][1].y = fmaf(xv, w1.y, acc[i][1].y);
          acc[i][1].z = fmaf(xv, w1.z, acc[i][1].z);
          acc[i][1].w = fmaf(xv, w1.w, acc[i][1].w);
        }
      }
    }
  }

  #pragma unroll
  for (int i = 0; i < 8; ++i) {
    int row = row0 + tr * 8 + i;
    if (row >= N) continue;
    if (MREAL >= 64 || c0 + 3 < MREAL)
      *(float4*)&Y[(size_t)row * MREAL + c0] = acc[i][0];
    if (MREAL >= 64 || c0 + 7 < MREAL)
      *(float4*)&Y[(size_t)row * MREAL + c0 + 4] = acc[i][1];
  }
}

// ---- bin conv: LDS 256xD accumulator, ds_add_f32 scatter, coalesced out ----
template<int D, bool RELU>
__launch_bounds__(256, (D == 64) ? 2 : 4)
__global__ void k_binconv(const float* __restrict__ H, const unsigned* __restrict__ binbuf,
                          const int* __restrict__ gbincnt, const float* __restrict__ dis,
                          const float* __restrict__ bias, float* __restrict__ out,
                          int N, int cap) {
  __shared__ float acc[256 * D];
  const int t = threadIdx.x, b = blockIdx.x;
  #pragma unroll
  for (int j = t; j < 256 * D / 4; j += 256)
    ((float4*)acc)[j] = make_float4(0.f, 0.f, 0.f, 0.f);
  __syncthreads();

  const int cnt = min(gbincnt[b], cap);
  const unsigned* buf = binbuf + (size_t)b * cap;
  const int lane = t & 63;
  const int wid = t >> 6;

  if (D == 64 || lane < D) {           // no barriers inside — legal divergence
    int i = wid;
    for (; i + 12 < cnt; i += 16) {    // 4 records in flight per wave
      unsigned r0 = buf[i], r1 = buf[i + 4], r2 = buf[i + 8], r3 = buf[i + 12];
      int s0 = r0 & 0x1FFFF, s1 = r1 & 0x1FFFF, s2 = r2 & 0x1FFFF, s3 = r3 & 0x1FFFF;
      float w0 = dis[s0], w1 = dis[s1], w2 = dis[s2], w3 = dis[s3];
      float v0 = H[(size_t)s0 * D + lane] * w0;
      float v1 = H[(size_t)s1 * D + lane] * w1;
      float v2 = H[(size_t)s2 * D + lane] * w2;
      float v3 = H[(size_t)s3 * D + lane] * w3;
      atomicAdd(&acc[(r0 >> 17) * D + lane], v0);
      atomicAdd(&acc[(r1 >> 17) * D + lane], v1);
      atomicAdd(&acc[(r2 >> 17) * D + lane], v2);
      atomicAdd(&acc[(r3 >> 17) * D + lane], v3);
    }
    for (; i < cnt; i += 4) {
      unsigned r0 = buf[i];
      int s0 = r0 & 0x1FFFF;
      float v0 = H[(size_t)s0 * D + lane] * dis[s0];
      atomicAdd(&acc[(r0 >> 17) * D + lane], v0);
    }
  }
  __syncthreads();

  // epilogue: out[node][col] = act(acc * dis[node] + bias[col]), coalesced
  for (int j = t; j < 256 * D; j += 256) {
    int nl = j / D, col = j - nl * D;
    int node = b * 256 + nl;
    if (node < N) {
      float v = fmaf(acc[j], dis[node], bias[col]);
      out[(size_t)node * D + col] = RELU ? fmaxf(v, 0.f) : v;
    }
  }
}

extern "C" void kernel_launch(void* const* d_in, const int* in_sizes, int n_in,
                              void* d_out, int out_size, void* d_ws, size_t ws_size,
                              hipStream_t stream) {
  const float* x  = (const float*)d_in[0];
  const int*   ed = (const int*)d_in[1];
  const float* W1 = (const float*)d_in[2];
  const float* b1 = (const float*)d_in[3];
  const float* W2 = (const float*)d_in[4];
  const float* b2 = (const float*)d_in[5];
  float* out = (float*)d_out;

  const int FIN = 128, FH = 64, FO = 40;
  const int N = in_sizes[0] / FIN;
  const int E = in_sizes[1] / 2;
  const int NBINS = (N + 255) >> 8;              // 391

  char* ws = (char*)d_ws;
  size_t off = 0;
  auto alloc = [&](size_t bytes) {
    void* p = ws + off;
    off = (off + bytes + 255) & ~(size_t)255;
    return p;
  };
  int*      flag    = (int*)alloc(4);
  int*      gbincnt = (int*)alloc(512 * 4);
  float*    dis     = (float*)alloc((size_t)N * 4);
  float*    h1      = (float*)alloc((size_t)N * FH * 4);   // gemm1 out
  float*    h1b     = (float*)alloc((size_t)N * FH * 4);   // conv1 out
  float*    h2      = h1;                                  // gemm2 out reuses h1
  // adaptive bin capacity from remaining workspace (mean load E/NBINS ~= 4092)
  size_t remain = (ws_size > off + 4096) ? (ws_size - off - 4096) : 0;
  int cap = (int)(remain / ((size_t)NBINS * 4));
  if (cap > 8192) cap = 8192;
  unsigned* binbuf  = (unsigned*)alloc((size_t)NBINS * cap * 4);

  hipMemsetAsync(gbincnt, 0, 512 * 4, stream);
  k_detect<<<1, 256, 0, stream>>>(ed, flag, in_sizes[1]);

  int fb = (E + 8191) / 8192;
  k_binfill<<<fb, 256, 0, stream>>>(ed, flag, gbincnt, binbuf, E, cap);
  k_bindeg<<<NBINS, 256, 0, stream>>>(binbuf, gbincnt, dis, N, cap);

  int gb = (N + 127) / 128;
  k_gemm<128, 64><<<gb, 128, 0, stream>>>(x, W1, h1, N);
  k_binconv<64, true><<<NBINS, 256, 0, stream>>>(h1, binbuf, gbincnt, dis, b1, h1b, N, cap);
  k_gemm<64, 40><<<gb, 128, 0, stream>>>(h1b, W2, h2, N);
  k_binconv<40, false><<<NBINS, 256, 0, stream>>>(h2, binbuf, gbincnt, dis, b2, out, N, cap);
}

// Round 4
// 354.894 us; speedup vs baseline: 3.7281x; 3.7281x over previous
//
#include <hip/hip_runtime.h>

// ---------------------------------------------------------------------------
// ReconGNN: out = conv(relu(conv(x@W1^T)+b1) @ W2^T) + b2
// conv = symmetric-normalized GCN aggregation over edge_index.
// R4: R3's bin-conv was latency-dead (391 blocks, occupancy 13%, 698us).
// Keep the bin machinery ONLY to build a per-node CSR with coalesced writes
// (k_fill's random 4B scatter cost 105MB write-allocate in R2); conv reverts
// to one-wave-per-node gather (100k waves = full latency hiding).
// Pipeline: memset(gbincnt) -> detect -> binfill -> binscan -> bindeg ->
//           binscatter -> gemm1 -> conv1(relu+b1) -> gemm2 -> conv2(+b2)
// Workspace: binbuf aliases h1 (binbuf dead before gemm1 writes h1).
// ---------------------------------------------------------------------------

// ---- edge dtype detection: int64 edges read as int32 have all-zero odd words
__global__ void k_detect(const int* __restrict__ ed, int* __restrict__ flag, int nwords) {
  __shared__ int any;
  if (threadIdx.x == 0) any = 0;
  __syncthreads();
  #pragma unroll
  for (int u = 0; u < 8; ++u) {
    int idx = 2 * (threadIdx.x * 8 + u) + 1;   // odd words 1..4095
    if (idx < nwords && ed[idx] != 0) any = 1; // benign race
  }
  __syncthreads();
  if (threadIdx.x == 0) *flag = any ? 0 : 1;   // 1 => int64 layout
}

// ---- bucket edges by destination bin (c>>8), coalesced run writes ----
// record = r | (c&255)<<17   (N <= 131072)
__global__ void k_binfill(const int* __restrict__ ed, const int* __restrict__ flag,
                          int* __restrict__ gbincnt, unsigned* __restrict__ binbuf,
                          int E, int cap) {
  __shared__ int hist[512];
  __shared__ int cursor[512];
  int t = threadIdx.x;
  hist[t] = 0; hist[t + 256] = 0;
  __syncthreads();
  const int is64 = *flag;
  const int base = blockIdx.x * 8192;
  const int nE = min(8192, E - base);
  for (int j = t; j < nE; j += 256) {
    int e = base + j;
    int c = is64 ? ed[2 * (E + e)] : ed[E + e];
    atomicAdd(&hist[c >> 8], 1);
  }
  __syncthreads();
  for (int b = t; b < 512; b += 256) {
    int h = hist[b];
    cursor[b] = h ? atomicAdd(&gbincnt[b], h) : 0;
  }
  __syncthreads();
  for (int j = t; j < nE; j += 256) {
    int e = base + j;
    int r = is64 ? ed[2 * e] : ed[e];
    int c = is64 ? ed[2 * (E + e)] : ed[E + e];
    int bin = c >> 8;
    int pos = atomicAdd(&cursor[bin], 1);
    if (pos < cap)
      binbuf[(size_t)bin * cap + pos] = (unsigned)r | ((unsigned)(c & 255) << 17);
  }
}

// ---- single-block exclusive scan over clamped bin counts -> gbase ----
__global__ void k_binscan(const int* __restrict__ gbincnt, int* __restrict__ gbase,
                          int* __restrict__ rowptr, int NBINS, int N, int cap) {
  __shared__ int sd[512];
  int t = threadIdx.x;
  #pragma unroll
  for (int u = 0; u < 2; ++u) {
    int i = t + 256 * u;
    sd[i] = (i < NBINS) ? min(gbincnt[i], cap) : 0;
  }
  __syncthreads();
  for (int off = 1; off < 512; off <<= 1) {
    int v0 = (t >= off) ? sd[t - off] : 0;
    int i1 = t + 256;
    int v1 = sd[i1 - off];
    __syncthreads();
    sd[t] += v0; sd[i1] += v1;
    __syncthreads();
  }
  #pragma unroll
  for (int u = 0; u < 2; ++u) {
    int i = t + 256 * u;
    if (i < NBINS) gbase[i] = (i == 0) ? 0 : sd[i - 1];
  }
  if (t == 0) rowptr[N] = sd[NBINS - 1];   // total kept records
}

// ---- per-bin degree + in-block scan -> dis[node], rowptr[node] ----
__global__ void k_bindeg(const unsigned* __restrict__ binbuf, const int* __restrict__ gbincnt,
                         const int* __restrict__ gbase, float* __restrict__ dis,
                         int* __restrict__ rowptr, int N, int cap) {
  __shared__ int cnt[256];
  __shared__ int sd[256];
  int t = threadIdx.x, b = blockIdx.x;
  cnt[t] = 0;
  __syncthreads();
  int n = min(gbincnt[b], cap);
  const unsigned* buf = binbuf + (size_t)b * cap;
  for (int j = t; j < n; j += 256) atomicAdd(&cnt[buf[j] >> 17], 1);
  __syncthreads();
  sd[t] = cnt[t];
  __syncthreads();
  for (int off = 1; off < 256; off <<= 1) {
    int v = (t >= off) ? sd[t - off] : 0;
    __syncthreads();
    sd[t] += v;
    __syncthreads();
  }
  int node = b * 256 + t;
  if (node < N) {
    int d = cnt[t];
    dis[node] = (d > 0) ? rsqrtf((float)d) : 0.f;
    rowptr[node] = gbase[b] + ((t == 0) ? 0 : sd[t - 1]);
  }
}

// ---- scatter bin records into per-node-contiguous srcs (16KB window/block) --
__global__ void k_binscatter(const unsigned* __restrict__ binbuf, const int* __restrict__ gbincnt,
                             const int* __restrict__ rowptr, int* __restrict__ srcs,
                             int N, int cap) {
  __shared__ int cursor[256];
  int t = threadIdx.x, b = blockIdx.x;
  int node = b * 256 + t;
  cursor[t] = (node < N) ? rowptr[node] : 0;
  __syncthreads();
  int n = min(gbincnt[b], cap);
  const unsigned* buf = binbuf + (size_t)b * cap;
  for (int j = t; j < n; j += 256) {
    unsigned rec = buf[j];
    int pos = atomicAdd(&cursor[rec >> 17], 1);
    srcs[pos] = (int)(rec & 0x1FFFF);
  }
}

// ---- GEMM: Y[N][MREAL] = X[N][KFULL] @ W[MREAL][KFULL]^T (R2, unchanged) ----
template<int KFULL, int MREAL>
__launch_bounds__(128)
__global__ void k_gemm(const float* __restrict__ X, const float* __restrict__ W,
                       float* __restrict__ Y, int N) {
  constexpr int BM = 128, BK = 32;
  __shared__ float xs[BM * BK];
  __shared__ float wt[BK * 64];
  const int tid = threadIdx.x;
  const int tr = tid >> 3;
  const int tc = tid & 7;
  const int row0 = blockIdx.x * BM;
  const int c0 = tc * 8;

  float4 acc[8][2];
  #pragma unroll
  for (int i = 0; i < 8; ++i) {
    acc[i][0] = make_float4(0.f, 0.f, 0.f, 0.f);
    acc[i][1] = make_float4(0.f, 0.f, 0.f, 0.f);
  }

  #pragma unroll 1
  for (int kt = 0; kt < KFULL / BK; ++kt) {
    if (kt) __syncthreads();
    #pragma unroll
    for (int j = 0; j < 8; ++j) {
      int q = tid + 128 * j;
      int r = q >> 3, kq = q & 7;
      float4 v = make_float4(0.f, 0.f, 0.f, 0.f);
      int row = row0 + r;
      if (row < N) v = *(const float4*)&X[(size_t)row * KFULL + kt * BK + kq * 4];
      *(float4*)&xs[r * 32 + ((kq ^ ((r >> 3) & 7)) << 2)] = v;
    }
    #pragma unroll
    for (int j = 0; j < 4; ++j) {
      int q = tid + 128 * j;
      int c = q >> 3, kq = q & 7;
      float4 v = make_float4(0.f, 0.f, 0.f, 0.f);
      if (c < MREAL) v = *(const float4*)&W[(size_t)c * KFULL + kt * BK + kq * 4];
      wt[(kq * 4 + 0) * 64 + c] = v.x;
      wt[(kq * 4 + 1) * 64 + c] = v.y;
      wt[(kq * 4 + 2) * 64 + c] = v.z;
      wt[(kq * 4 + 3) * 64 + c] = v.w;
    }
    __syncthreads();

    #pragma unroll 2
    for (int kq = 0; kq < 8; ++kq) {
      float4 xr[8];
      #pragma unroll
      for (int i = 0; i < 8; ++i)
        xr[i] = *(const float4*)&xs[(tr * 8 + i) * 32 + ((kq ^ (tr & 7)) << 2)];
      #pragma unroll
      for (int kk = 0; kk < 4; ++kk) {
        int k = kq * 4 + kk;
        float4 w0 = *(const float4*)&wt[k * 64 + c0];
        float4 w1 = *(const float4*)&wt[k * 64 + c0 + 4];
        #pragma unroll
        for (int i = 0; i < 8; ++i) {
          float xv = ((const float*)&xr[i])[kk];
          acc[i][0].x = fmaf(xv, w0.x, acc[i][0].x);
          acc[i][0].y = fmaf(xv, w0.y, acc[i][0].y);
          acc[i][0].z = fmaf(xv, w0.z, acc[i][0].z);
          acc[i][0].w = fmaf(xv, w0.w, acc[i][0].w);
          acc[i][1].x = fmaf(xv, w1.x, acc[i][1].x);
          acc[i][1].y = fmaf(xv, w1.y, acc[i][1].y);
          acc[i][1].z = fmaf(xv, w1.z, acc[i][1].z);
          acc[i][1].w = fmaf(xv, w1.w, acc[i][1].w);
        }
      }
    }
  }

  #pragma unroll
  for (int i = 0; i < 8; ++i) {
    int row = row0 + tr * 8 + i;
    if (row >= N) continue;
    if (MREAL >= 64 || c0 + 3 < MREAL)
      *(float4*)&Y[(size_t)row * MREAL + c0] = acc[i][0];
    if (MREAL >= 64 || c0 + 7 < MREAL)
      *(float4*)&Y[(size_t)row * MREAL + c0 + 4] = acc[i][1];
  }
}

// ---- GCN conv: one wave per node, lane = feature, 4 edges in flight ----
template<int D, bool RELU>
__launch_bounds__(256)
__global__ void k_conv(const float* __restrict__ H, const int* __restrict__ rowptr,
                       const int* __restrict__ srcs, const float* __restrict__ dis,
                       const float* __restrict__ bias, float* __restrict__ out, int N) {
  int node = blockIdx.x * 4 + (threadIdx.x >> 6);
  int lane = threadIdx.x & 63;
  if (node >= N) return;
  int s = rowptr[node], e = rowptr[node + 1];
  float acc = 0.f;
  int p = s;
  for (; p + 4 <= e; p += 4) {
    int s0 = srcs[p], s1 = srcs[p + 1], s2 = srcs[p + 2], s3 = srcs[p + 3];
    float w0 = dis[s0], w1 = dis[s1], w2 = dis[s2], w3 = dis[s3];
    float h0 = 0.f, h1 = 0.f, h2 = 0.f, h3 = 0.f;
    if (D == 64 || lane < D) {
      h0 = H[(size_t)s0 * D + lane];
      h1 = H[(size_t)s1 * D + lane];
      h2 = H[(size_t)s2 * D + lane];
      h3 = H[(size_t)s3 * D + lane];
    }
    acc = fmaf(h0, w0, acc);
    acc = fmaf(h1, w1, acc);
    acc = fmaf(h2, w2, acc);
    acc = fmaf(h3, w3, acc);
  }
  for (; p < e; ++p) {
    int s0 = srcs[p];
    float w0 = dis[s0];
    float h0 = (D == 64 || lane < D) ? H[(size_t)s0 * D + lane] : 0.f;
    acc = fmaf(h0, w0, acc);
  }
  if (lane < D) {
    float v = fmaf(acc, dis[node], bias[lane]);
    out[(size_t)node * D + lane] = RELU ? fmaxf(v, 0.f) : v;
  }
}

extern "C" void kernel_launch(void* const* d_in, const int* in_sizes, int n_in,
                              void* d_out, int out_size, void* d_ws, size_t ws_size,
                              hipStream_t stream) {
  const float* x  = (const float*)d_in[0];
  const int*   ed = (const int*)d_in[1];
  const float* W1 = (const float*)d_in[2];
  const float* b1 = (const float*)d_in[3];
  const float* W2 = (const float*)d_in[4];
  const float* b2 = (const float*)d_in[5];
  float* out = (float*)d_out;

  const int FIN = 128, FH = 64, FO = 40;
  const int N = in_sizes[0] / FIN;
  const int E = in_sizes[1] / 2;
  const int NBINS = (N + 255) >> 8;              // 391

  char* ws = (char*)d_ws;
  size_t off = 0;
  auto alloc = [&](size_t bytes) {
    void* p = ws + off;
    off = (off + bytes + 255) & ~(size_t)255;
    return p;
  };
  int*      flag    = (int*)alloc(4);
  int*      gbincnt = (int*)alloc(512 * 4);
  int*      gbase   = (int*)alloc(512 * 4);
  float*    dis     = (float*)alloc((size_t)N * 4);
  int*      rowptr  = (int*)alloc(((size_t)N + 1) * 4);
  int*      srcs    = (int*)alloc((size_t)E * 4);
  float*    h1      = (float*)alloc((size_t)N * FH * 4);   // gemm1 out; aliases binbuf
  float*    h1b     = (float*)alloc((size_t)N * FH * 4);   // conv1 out
  float*    h2      = h1;                                  // gemm2 out reuses h1
  // binbuf aliases h1: dead before gemm1 writes h1 (same-stream ordering)
  int cap = (int)(((size_t)N * FH * 4) / ((size_t)NBINS * 4));
  if (cap > 8192) cap = 8192;                    // mean bin load ~4092
  unsigned* binbuf  = (unsigned*)h1;

  hipMemsetAsync(gbincnt, 0, 512 * 4, stream);
  k_detect<<<1, 256, 0, stream>>>(ed, flag, in_sizes[1]);

  int fb = (E + 8191) / 8192;
  k_binfill<<<fb, 256, 0, stream>>>(ed, flag, gbincnt, binbuf, E, cap);
  k_binscan<<<1, 256, 0, stream>>>(gbincnt, gbase, rowptr, NBINS, N, cap);
  k_bindeg<<<NBINS, 256, 0, stream>>>(binbuf, gbincnt, gbase, dis, rowptr, N, cap);
  k_binscatter<<<NBINS, 256, 0, stream>>>(binbuf, gbincnt, rowptr, srcs, N, cap);

  int gb = (N + 127) / 128;
  int cb = (N + 3) / 4;
  k_gemm<128, 64><<<gb, 128, 0, stream>>>(x, W1, h1, N);
  k_conv<64, true><<<cb, 256, 0, stream>>>(h1, rowptr, srcs, dis, b1, h1b, N);
  k_gemm<64, 40><<<gb, 128, 0, stream>>>(h1b, W2, h2, N);
  k_conv<40, false><<<cb, 256, 0, stream>>>(h2, rowptr, srcs, dis, b2, out, N);
}

// Round 5
// 339.933 us; speedup vs baseline: 3.8921x; 1.0440x over previous
//
#include <hip/hip_runtime.h>
#include <hip/hip_fp16.h>

// ---------------------------------------------------------------------------
// ReconGNN: out = conv(relu(conv(x@W1^T)+b1) @ W2^T) + b2
// R5: conv gather was TCC-bandwidth bound (183MB fetch, 74us). All
// intermediates now fp16 (halves every conv/gemm-out byte), rows pre-scaled
// by dis in the gemm epilogue (kills per-edge dis[src] loads), conv1 uses
// half2 2-edges-per-wave + shfl combine, bindeg+binscatter fused.
// Pipeline: memset -> detect -> binfill -> binscan -> degscat ->
//           gemm1(fp32 in, fp16*dis out) -> conv64(relu+b1, fp16 out) ->
//           gemm2(fp16 in, fp16*dis out) -> conv40(+b2, fp32 out)
// Aliases: binbuf==h1 (dead before gemm1), h2==h1 (dead after conv1).
// ---------------------------------------------------------------------------

// ---- edge dtype detection: int64 edges read as int32 have all-zero odd words
__global__ void k_detect(const int* __restrict__ ed, int* __restrict__ flag, int nwords) {
  __shared__ int any;
  if (threadIdx.x == 0) any = 0;
  __syncthreads();
  #pragma unroll
  for (int u = 0; u < 8; ++u) {
    int idx = 2 * (threadIdx.x * 8 + u) + 1;
    if (idx < nwords && ed[idx] != 0) any = 1;
  }
  __syncthreads();
  if (threadIdx.x == 0) *flag = any ? 0 : 1;   // 1 => int64 layout
}

// ---- bucket edges by destination bin (c>>8), coalesced run writes ----
// record = r | (c&255)<<17   (N <= 131072)
__global__ void k_binfill(const int* __restrict__ ed, const int* __restrict__ flag,
                          int* __restrict__ gbincnt, unsigned* __restrict__ binbuf,
                          int E, int cap) {
  __shared__ int hist[512];
  __shared__ int cursor[512];
  int t = threadIdx.x;
  hist[t] = 0; hist[t + 256] = 0;
  __syncthreads();
  const int is64 = *flag;
  const int base = blockIdx.x * 8192;
  const int nE = min(8192, E - base);
  for (int j = t; j < nE; j += 256) {
    int e = base + j;
    int c = is64 ? ed[2 * (E + e)] : ed[E + e];
    atomicAdd(&hist[c >> 8], 1);
  }
  __syncthreads();
  for (int b = t; b < 512; b += 256) {
    int h = hist[b];
    cursor[b] = h ? atomicAdd(&gbincnt[b], h) : 0;
  }
  __syncthreads();
  for (int j = t; j < nE; j += 256) {
    int e = base + j;
    int r = is64 ? ed[2 * e] : ed[e];
    int c = is64 ? ed[2 * (E + e)] : ed[E + e];
    int bin = c >> 8;
    int pos = atomicAdd(&cursor[bin], 1);
    if (pos < cap)
      binbuf[(size_t)bin * cap + pos] = (unsigned)r | ((unsigned)(c & 255) << 17);
  }
}

// ---- single-block exclusive scan over clamped bin counts -> gbase ----
__global__ void k_binscan(const int* __restrict__ gbincnt, int* __restrict__ gbase,
                          int* __restrict__ rowptr, int NBINS, int N, int cap) {
  __shared__ int sd[512];
  int t = threadIdx.x;
  #pragma unroll
  for (int u = 0; u < 2; ++u) {
    int i = t + 256 * u;
    sd[i] = (i < NBINS) ? min(gbincnt[i], cap) : 0;
  }
  __syncthreads();
  for (int off = 1; off < 512; off <<= 1) {
    int v0 = (t >= off) ? sd[t - off] : 0;
    int i1 = t + 256;
    int v1 = sd[i1 - off];
    __syncthreads();
    sd[t] += v0; sd[i1] += v1;
    __syncthreads();
  }
  #pragma unroll
  for (int u = 0; u < 2; ++u) {
    int i = t + 256 * u;
    if (i < NBINS) gbase[i] = (i == 0) ? 0 : sd[i - 1];
  }
  if (t == 0) rowptr[N] = sd[NBINS - 1];
}

// ---- fused: per-bin degree + scan -> dis/rowptr, then scatter srcs ----
__global__ void k_degscat(const unsigned* __restrict__ binbuf, const int* __restrict__ gbincnt,
                          const int* __restrict__ gbase, float* __restrict__ dis,
                          int* __restrict__ rowptr, int* __restrict__ srcs, int N, int cap) {
  __shared__ int cnt[256];
  __shared__ int sd[256];
  __shared__ int cursor[256];
  int t = threadIdx.x, b = blockIdx.x;
  cnt[t] = 0;
  __syncthreads();
  int n = min(gbincnt[b], cap);
  const unsigned* buf = binbuf + (size_t)b * cap;
  for (int j = t; j < n; j += 256) atomicAdd(&cnt[buf[j] >> 17], 1);
  __syncthreads();
  sd[t] = cnt[t];
  __syncthreads();
  for (int off = 1; off < 256; off <<= 1) {
    int v = (t >= off) ? sd[t - off] : 0;
    __syncthreads();
    sd[t] += v;
    __syncthreads();
  }
  int rp = gbase[b] + ((t == 0) ? 0 : sd[t - 1]);
  cursor[t] = rp;
  int node = b * 256 + t;
  if (node < N) {
    int d = cnt[t];
    dis[node] = (d > 0) ? rsqrtf((float)d) : 0.f;
    rowptr[node] = rp;
  }
  __syncthreads();
  for (int j = t; j < n; j += 256) {
    unsigned rec = buf[j];
    int pos = atomicAdd(&cursor[rec >> 17], 1);
    srcs[pos] = (int)(rec & 0x1FFFF);
  }
}

// ---- GEMM: Y[N][MREAL] = (X[N][KFULL] @ W[MREAL][KFULL]^T) * dis[row], fp16 out
template<int KFULL, int MREAL, bool XHALF>
__launch_bounds__(128)
__global__ void k_gemm(const void* __restrict__ Xv, const float* __restrict__ W,
                       const float* __restrict__ dis, __half* __restrict__ Y, int N) {
  constexpr int BM = 128, BK = 32;
  __shared__ float xs[BM * BK];
  __shared__ float wt[BK * 64];
  const float*  Xf = (const float*)Xv;
  const __half* Xh = (const __half*)Xv;
  const int tid = threadIdx.x;
  const int tr = tid >> 3;
  const int tc = tid & 7;
  const int row0 = blockIdx.x * BM;
  const int c0 = tc * 8;

  float4 acc[8][2];
  #pragma unroll
  for (int i = 0; i < 8; ++i) {
    acc[i][0] = make_float4(0.f, 0.f, 0.f, 0.f);
    acc[i][1] = make_float4(0.f, 0.f, 0.f, 0.f);
  }

  #pragma unroll 1
  for (int kt = 0; kt < KFULL / BK; ++kt) {
    if (kt) __syncthreads();
    #pragma unroll
    for (int j = 0; j < 8; ++j) {
      int q = tid + 128 * j;
      int r = q >> 3, kq = q & 7;
      float4 v = make_float4(0.f, 0.f, 0.f, 0.f);
      int row = row0 + r;
      if (row < N) {
        size_t idx = (size_t)row * KFULL + kt * BK + kq * 4;
        if (XHALF) {
          float2 raw = *(const float2*)&Xh[idx];        // 4 halves
          const __half* hp = (const __half*)&raw;
          v = make_float4(__half2float(hp[0]), __half2float(hp[1]),
                          __half2float(hp[2]), __half2float(hp[3]));
        } else {
          v = *(const float4*)&Xf[idx];
        }
      }
      *(float4*)&xs[r * 32 + ((kq ^ ((r >> 3) & 7)) << 2)] = v;
    }
    #pragma unroll
    for (int j = 0; j < 4; ++j) {
      int q = tid + 128 * j;
      int c = q >> 3, kq = q & 7;
      float4 v = make_float4(0.f, 0.f, 0.f, 0.f);
      if (c < MREAL) v = *(const float4*)&W[(size_t)c * KFULL + kt * BK + kq * 4];
      wt[(kq * 4 + 0) * 64 + c] = v.x;
      wt[(kq * 4 + 1) * 64 + c] = v.y;
      wt[(kq * 4 + 2) * 64 + c] = v.z;
      wt[(kq * 4 + 3) * 64 + c] = v.w;
    }
    __syncthreads();

    #pragma unroll 2
    for (int kq = 0; kq < 8; ++kq) {
      float4 xr[8];
      #pragma unroll
      for (int i = 0; i < 8; ++i)
        xr[i] = *(const float4*)&xs[(tr * 8 + i) * 32 + ((kq ^ (tr & 7)) << 2)];
      #pragma unroll
      for (int kk = 0; kk < 4; ++kk) {
        int k = kq * 4 + kk;
        float4 w0 = *(const float4*)&wt[k * 64 + c0];
        float4 w1 = *(const float4*)&wt[k * 64 + c0 + 4];
        #pragma unroll
        for (int i = 0; i < 8; ++i) {
          float xv = ((const float*)&xr[i])[kk];
          acc[i][0].x = fmaf(xv, w0.x, acc[i][0].x);
          acc[i][0].y = fmaf(xv, w0.y, acc[i][0].y);
          acc[i][0].z = fmaf(xv, w0.z, acc[i][0].z);
          acc[i][0].w = fmaf(xv, w0.w, acc[i][0].w);
          acc[i][1].x = fmaf(xv, w1.x, acc[i][1].x);
          acc[i][1].y = fmaf(xv, w1.y, acc[i][1].y);
          acc[i][1].z = fmaf(xv, w1.z, acc[i][1].z);
          acc[i][1].w = fmaf(xv, w1.w, acc[i][1].w);
        }
      }
    }
  }

  // epilogue: scale row by dis, store 8 cols as 16B of fp16
  #pragma unroll
  for (int i = 0; i < 8; ++i) {
    int row = row0 + tr * 8 + i;
    if (row >= N) continue;
    if (MREAL >= 64 || c0 + 7 < MREAL) {
      float dr = dis[row];
      __half hv[8];
      const float* a = (const float*)&acc[i][0];
      #pragma unroll
      for (int j = 0; j < 8; ++j) hv[j] = __float2half_rn(a[j] * dr);
      *(float4*)&Y[(size_t)row * MREAL + c0] = *(float4*)hv;
    }
  }
}

// ---- conv1 (D=64, fp16): 2 edges per wave via half-split, shfl combine ----
__launch_bounds__(256)
__global__ void k_conv64(const __half* __restrict__ H, const int* __restrict__ rowptr,
                         const int* __restrict__ srcs, const float* __restrict__ dis,
                         const float* __restrict__ bias, __half* __restrict__ out, int N) {
  int node = blockIdx.x * 4 + (threadIdx.x >> 6);
  if (node >= N) return;                 // wave-uniform
  int lane = threadIdx.x & 63;
  int sub = lane & 31, hf = lane >> 5;   // hf: which edge of the pair
  int s = rowptr[node], e = rowptr[node + 1];
  float ax = 0.f, ay = 0.f;
  int p = s + hf;
  for (; p + 2 < e; p += 4) {            // 2 edges in flight per half-wave
    int s0 = srcs[p], s1 = srcs[p + 2];
    float2 f0 = __half22float2(*(const __half2*)&H[(size_t)s0 * 64 + 2 * sub]);
    float2 f1 = __half22float2(*(const __half2*)&H[(size_t)s1 * 64 + 2 * sub]);
    ax += f0.x; ay += f0.y;
    ax += f1.x; ay += f1.y;
  }
  if (p < e) {
    int s0 = srcs[p];
    float2 f0 = __half22float2(*(const __half2*)&H[(size_t)s0 * 64 + 2 * sub]);
    ax += f0.x; ay += f0.y;
  }
  ax += __shfl_xor(ax, 32);
  ay += __shfl_xor(ay, 32);
  if (hf == 0) {
    float dn = dis[node];
    float vx = fmaxf(fmaf(ax, dn, bias[2 * sub]), 0.f);
    float vy = fmaxf(fmaf(ay, dn, bias[2 * sub + 1]), 0.f);
    *(__half2*)&out[(size_t)node * 64 + 2 * sub] = __floats2half2_rn(vx, vy);
  }
}

// ---- conv2 (D=40, fp16 in, fp32 out): wave per node, 4 edges in flight ----
__launch_bounds__(256)
__global__ void k_conv40(const __half* __restrict__ H, const int* __restrict__ rowptr,
                         const int* __restrict__ srcs, const float* __restrict__ dis,
                         const float* __restrict__ bias, float* __restrict__ out, int N) {
  int node = blockIdx.x * 4 + (threadIdx.x >> 6);
  if (node >= N) return;
  int lane = threadIdx.x & 63;
  bool act = lane < 40;
  int s = rowptr[node], e = rowptr[node + 1];
  float acc = 0.f;
  int p = s;
  for (; p + 4 <= e; p += 4) {
    int s0 = srcs[p], s1 = srcs[p + 1], s2 = srcs[p + 2], s3 = srcs[p + 3];
    float h0 = 0.f, h1 = 0.f, h2 = 0.f, h3 = 0.f;
    if (act) {
      h0 = __half2float(H[(size_t)s0 * 40 + lane]);
      h1 = __half2float(H[(size_t)s1 * 40 + lane]);
      h2 = __half2float(H[(size_t)s2 * 40 + lane]);
      h3 = __half2float(H[(size_t)s3 * 40 + lane]);
    }
    acc += h0; acc += h1; acc += h2; acc += h3;
  }
  for (; p < e; ++p) {
    int s0 = srcs[p];
    if (act) acc += __half2float(H[(size_t)s0 * 40 + lane]);
  }
  if (act) {
    float v = fmaf(acc, dis[node], bias[lane]);
    out[(size_t)node * 40 + lane] = v;
  }
}

extern "C" void kernel_launch(void* const* d_in, const int* in_sizes, int n_in,
                              void* d_out, int out_size, void* d_ws, size_t ws_size,
                              hipStream_t stream) {
  const float* x  = (const float*)d_in[0];
  const int*   ed = (const int*)d_in[1];
  const float* W1 = (const float*)d_in[2];
  const float* b1 = (const float*)d_in[3];
  const float* W2 = (const float*)d_in[4];
  const float* b2 = (const float*)d_in[5];
  float* out = (float*)d_out;

  const int FIN = 128, FH = 64, FO = 40;
  const int N = in_sizes[0] / FIN;
  const int E = in_sizes[1] / 2;
  const int NBINS = (N + 255) >> 8;              // 391

  char* ws = (char*)d_ws;
  size_t off = 0;
  auto alloc = [&](size_t bytes) {
    void* p = ws + off;
    off = (off + bytes + 255) & ~(size_t)255;
    return p;
  };
  int*    flag    = (int*)alloc(4);
  int*    gbincnt = (int*)alloc(512 * 4);
  int*    gbase   = (int*)alloc(512 * 4);
  float*  dis     = (float*)alloc((size_t)N * 4);
  int*    rowptr  = (int*)alloc(((size_t)N + 1) * 4);
  int*    srcs    = (int*)alloc((size_t)E * 4);
  __half* h1      = (__half*)alloc((size_t)N * FH * 2);   // gemm1 out; aliases binbuf
  __half* h1b     = (__half*)alloc((size_t)N * FH * 2);   // conv1 out
  __half* h2      = h1;                                   // gemm2 out reuses h1
  // binbuf aliases h1 (dead before gemm1 writes h1; same-stream ordering)
  int cap = (int)(((size_t)N * FH * 2) / ((size_t)NBINS * 4));
  if (cap > 8192) cap = 8192;                    // mean bin load ~4092
  unsigned* binbuf = (unsigned*)h1;

  hipMemsetAsync(gbincnt, 0, 512 * 4, stream);
  k_detect<<<1, 256, 0, stream>>>(ed, flag, in_sizes[1]);

  int fb = (E + 8191) / 8192;
  k_binfill<<<fb, 256, 0, stream>>>(ed, flag, gbincnt, binbuf, E, cap);
  k_binscan<<<1, 256, 0, stream>>>(gbincnt, gbase, rowptr, NBINS, N, cap);
  k_degscat<<<NBINS, 256, 0, stream>>>(binbuf, gbincnt, gbase, dis, rowptr, srcs, N, cap);

  int gb = (N + 127) / 128;
  int cb = (N + 3) / 4;
  k_gemm<128, 64, false><<<gb, 128, 0, stream>>>(x, W1, dis, h1, N);
  k_conv64<<<cb, 256, 0, stream>>>(h1, rowptr, srcs, dis, b1, h1b, N);
  k_gemm<64, 40, true><<<gb, 128, 0, stream>>>(h1b, W2, dis, h2, N);
  k_conv40<<<cb, 256, 0, stream>>>(h2, rowptr, srcs, dis, b2, out, N);
}

// Round 6
// 331.852 us; speedup vs baseline: 3.9869x; 1.0244x over previous
//
#include <hip/hip_runtime.h>
#include <hip/hip_fp16.h>

// ---------------------------------------------------------------------------
// ReconGNN: out = conv(relu(conv(x@W1^T)+b1) @ W2^T) + b2
// R6: convs were latency-bound (4 edges in flight x 22 waves ~= 600cy miss
// latency -> 67us). Now 16 edges in flight per wave (half-wave split +
// unroll 8). gemm1 moved to MFMA f16 (16x16x32), whole W1 in LDS, XOR-swizzle.
// Pipeline: memset -> detect -> binfill -> binscan -> degscat ->
//           gemm1_mfma(fp32 in, fp16*dis out) -> conv64(relu+b1) ->
//           gemm2 VALU(fp16 in, fp16*dis out) -> conv40(+b2, fp32 out)
// Aliases: binbuf==h1 (dead before gemm1), h2==h1 (dead after conv1).
// ---------------------------------------------------------------------------

typedef __attribute__((ext_vector_type(8))) _Float16 half8v;
typedef __attribute__((ext_vector_type(4))) float   float4v;

// ---- edge dtype detection: int64 edges read as int32 have all-zero odd words
__global__ void k_detect(const int* __restrict__ ed, int* __restrict__ flag, int nwords) {
  __shared__ int any;
  if (threadIdx.x == 0) any = 0;
  __syncthreads();
  #pragma unroll
  for (int u = 0; u < 8; ++u) {
    int idx = 2 * (threadIdx.x * 8 + u) + 1;
    if (idx < nwords && ed[idx] != 0) any = 1;
  }
  __syncthreads();
  if (threadIdx.x == 0) *flag = any ? 0 : 1;   // 1 => int64 layout
}

// ---- bucket edges by destination bin (c>>8), coalesced run writes ----
// record = r | (c&255)<<17   (N <= 131072)
__global__ void k_binfill(const int* __restrict__ ed, const int* __restrict__ flag,
                          int* __restrict__ gbincnt, unsigned* __restrict__ binbuf,
                          int E, int cap) {
  __shared__ int hist[512];
  __shared__ int cursor[512];
  int t = threadIdx.x;
  hist[t] = 0; hist[t + 256] = 0;
  __syncthreads();
  const int is64 = *flag;
  const int base = blockIdx.x * 8192;
  const int nE = min(8192, E - base);
  for (int j = t; j < nE; j += 256) {
    int e = base + j;
    int c = is64 ? ed[2 * (E + e)] : ed[E + e];
    atomicAdd(&hist[c >> 8], 1);
  }
  __syncthreads();
  for (int b = t; b < 512; b += 256) {
    int h = hist[b];
    cursor[b] = h ? atomicAdd(&gbincnt[b], h) : 0;
  }
  __syncthreads();
  for (int j = t; j < nE; j += 256) {
    int e = base + j;
    int r = is64 ? ed[2 * e] : ed[e];
    int c = is64 ? ed[2 * (E + e)] : ed[E + e];
    int bin = c >> 8;
    int pos = atomicAdd(&cursor[bin], 1);
    if (pos < cap)
      binbuf[(size_t)bin * cap + pos] = (unsigned)r | ((unsigned)(c & 255) << 17);
  }
}

// ---- single-block exclusive scan over clamped bin counts -> gbase ----
__global__ void k_binscan(const int* __restrict__ gbincnt, int* __restrict__ gbase,
                          int* __restrict__ rowptr, int NBINS, int N, int cap) {
  __shared__ int sd[512];
  int t = threadIdx.x;
  #pragma unroll
  for (int u = 0; u < 2; ++u) {
    int i = t + 256 * u;
    sd[i] = (i < NBINS) ? min(gbincnt[i], cap) : 0;
  }
  __syncthreads();
  for (int off = 1; off < 512; off <<= 1) {
    int v0 = (t >= off) ? sd[t - off] : 0;
    int i1 = t + 256;
    int v1 = sd[i1 - off];
    __syncthreads();
    sd[t] += v0; sd[i1] += v1;
    __syncthreads();
  }
  #pragma unroll
  for (int u = 0; u < 2; ++u) {
    int i = t + 256 * u;
    if (i < NBINS) gbase[i] = (i == 0) ? 0 : sd[i - 1];
  }
  if (t == 0) rowptr[N] = sd[NBINS - 1];
}

// ---- fused: per-bin degree + scan -> dis/rowptr, then scatter srcs ----
__global__ void k_degscat(const unsigned* __restrict__ binbuf, const int* __restrict__ gbincnt,
                          const int* __restrict__ gbase, float* __restrict__ dis,
                          int* __restrict__ rowptr, int* __restrict__ srcs, int N, int cap) {
  __shared__ int cnt[256];
  __shared__ int sd[256];
  __shared__ int cursor[256];
  int t = threadIdx.x, b = blockIdx.x;
  cnt[t] = 0;
  __syncthreads();
  int n = min(gbincnt[b], cap);
  const unsigned* buf = binbuf + (size_t)b * cap;
  for (int j = t; j < n; j += 256) atomicAdd(&cnt[buf[j] >> 17], 1);
  __syncthreads();
  sd[t] = cnt[t];
  __syncthreads();
  for (int off = 1; off < 256; off <<= 1) {
    int v = (t >= off) ? sd[t - off] : 0;
    __syncthreads();
    sd[t] += v;
    __syncthreads();
  }
  int rp = gbase[b] + ((t == 0) ? 0 : sd[t - 1]);
  cursor[t] = rp;
  int node = b * 256 + t;
  if (node < N) {
    int d = cnt[t];
    dis[node] = (d > 0) ? rsqrtf((float)d) : 0.f;
    rowptr[node] = rp;
  }
  __syncthreads();
  for (int j = t; j < n; j += 256) {
    unsigned rec = buf[j];
    int pos = atomicAdd(&cursor[rec >> 17], 1);
    srcs[pos] = (int)(rec & 0x1FFFF);
  }
}

// ---- gemm1 (MFMA f16): Y[N][64] = (X[N][128] @ W[64][128]^T) * dis, fp16 out
// Block 256 thr = 4 waves, 128 rows/block. A/B frags: [idx=lane&15][k=quad*8+j]
// C/D: col=lane&15, row=quad*4+reg. 16B-chunk XOR swizzle on k (2-way = free).
__launch_bounds__(256)
__global__ void k_gemm1_mfma(const float* __restrict__ X, const float* __restrict__ W,
                             const float* __restrict__ dis, __half* __restrict__ Y, int N) {
  __shared__ _Float16 xl[128 * 128];   // 32 KB
  __shared__ _Float16 wl[64 * 128];    // 16 KB
  const int t = threadIdx.x;
  const int row0 = blockIdx.x * 128;

  // stage W1 -> LDS fp16 (swizzled): thread t covers n=t>>2, k in [(t&3)*32, +32)
  {
    int n = t >> 2, kb = (t & 3) * 32;
    const float* src = W + n * 128 + kb;
    #pragma unroll
    for (int j = 0; j < 4; ++j) {
      float4 va = *(const float4*)&src[j * 8];
      float4 vb = *(const float4*)&src[j * 8 + 4];
      _Float16 h8[8] = {(_Float16)va.x, (_Float16)va.y, (_Float16)va.z, (_Float16)va.w,
                        (_Float16)vb.x, (_Float16)vb.y, (_Float16)vb.z, (_Float16)vb.w};
      int k = kb + j * 8;
      *(float4*)&wl[n * 128 + (k ^ ((n & 7) * 8))] = *(float4*)h8;
    }
  }
  // stage X tile -> LDS fp16 (swizzled): thread t covers r=t>>1, k half (t&1)
  {
    int r = t >> 1, kb = (t & 1) * 64;
    int row = row0 + r;
    #pragma unroll
    for (int j = 0; j < 8; ++j) {
      float4 va = make_float4(0.f, 0.f, 0.f, 0.f), vb = va;
      if (row < N) {
        va = *(const float4*)&X[(size_t)row * 128 + kb + j * 8];
        vb = *(const float4*)&X[(size_t)row * 128 + kb + j * 8 + 4];
      }
      _Float16 h8[8] = {(_Float16)va.x, (_Float16)va.y, (_Float16)va.z, (_Float16)va.w,
                        (_Float16)vb.x, (_Float16)vb.y, (_Float16)vb.z, (_Float16)vb.w};
      int k = kb + j * 8;
      *(float4*)&xl[r * 128 + (k ^ ((r & 7) * 8))] = *(float4*)h8;
    }
  }
  __syncthreads();

  const int w = t >> 6, l = t & 63;
  const int m0 = w * 32;
  const int lr = l & 15, q = l >> 4;

  float4v acc[2][4] = {};
  #pragma unroll
  for (int kc = 0; kc < 4; ++kc) {
    half8v a[2], b[4];
    #pragma unroll
    for (int mt = 0; mt < 2; ++mt) {
      int m = m0 + mt * 16 + lr;
      int k = (kc * 32 + q * 8) ^ ((m & 7) * 8);
      a[mt] = *(half8v*)&xl[m * 128 + k];
    }
    #pragma unroll
    for (int nt = 0; nt < 4; ++nt) {
      int n = nt * 16 + lr;
      int k = (kc * 32 + q * 8) ^ ((n & 7) * 8);
      b[nt] = *(half8v*)&wl[n * 128 + k];
    }
    #pragma unroll
    for (int mt = 0; mt < 2; ++mt)
      #pragma unroll
      for (int nt = 0; nt < 4; ++nt)
        acc[mt][nt] = __builtin_amdgcn_mfma_f32_16x16x32_f16(a[mt], b[nt], acc[mt][nt], 0, 0, 0);
  }

  #pragma unroll
  for (int mt = 0; mt < 2; ++mt) {
    #pragma unroll
    for (int r = 0; r < 4; ++r) {
      int row = row0 + m0 + mt * 16 + q * 4 + r;
      if (row < N) {
        float dr = dis[row];
        #pragma unroll
        for (int nt = 0; nt < 4; ++nt)
          Y[(size_t)row * 64 + nt * 16 + lr] = __float2half_rn(acc[mt][nt][r] * dr);
      }
    }
  }
}

// ---- GEMM (VALU, gemm2): Y = (X @ W^T) * dis, fp16 in/out ----
template<int KFULL, int MREAL>
__launch_bounds__(128)
__global__ void k_gemm(const __half* __restrict__ Xh, const float* __restrict__ W,
                       const float* __restrict__ dis, __half* __restrict__ Y, int N) {
  constexpr int BM = 128, BK = 32;
  __shared__ float xs[BM * BK];
  __shared__ float wt[BK * 64];
  const int tid = threadIdx.x;
  const int tr = tid >> 3;
  const int tc = tid & 7;
  const int row0 = blockIdx.x * BM;
  const int c0 = tc * 8;

  float4 acc[8][2];
  #pragma unroll
  for (int i = 0; i < 8; ++i) {
    acc[i][0] = make_float4(0.f, 0.f, 0.f, 0.f);
    acc[i][1] = make_float4(0.f, 0.f, 0.f, 0.f);
  }

  #pragma unroll 1
  for (int kt = 0; kt < KFULL / BK; ++kt) {
    if (kt) __syncthreads();
    #pragma unroll
    for (int j = 0; j < 8; ++j) {
      int q = tid + 128 * j;
      int r = q >> 3, kq = q & 7;
      float4 v = make_float4(0.f, 0.f, 0.f, 0.f);
      int row = row0 + r;
      if (row < N) {
        float2 raw = *(const float2*)&Xh[(size_t)row * KFULL + kt * BK + kq * 4];
        const __half* hp = (const __half*)&raw;
        v = make_float4(__half2float(hp[0]), __half2float(hp[1]),
                        __half2float(hp[2]), __half2float(hp[3]));
      }
      *(float4*)&xs[r * 32 + ((kq ^ ((r >> 3) & 7)) << 2)] = v;
    }
    #pragma unroll
    for (int j = 0; j < 4; ++j) {
      int q = tid + 128 * j;
      int c = q >> 3, kq = q & 7;
      float4 v = make_float4(0.f, 0.f, 0.f, 0.f);
      if (c < MREAL) v = *(const float4*)&W[(size_t)c * KFULL + kt * BK + kq * 4];
      wt[(kq * 4 + 0) * 64 + c] = v.x;
      wt[(kq * 4 + 1) * 64 + c] = v.y;
      wt[(kq * 4 + 2) * 64 + c] = v.z;
      wt[(kq * 4 + 3) * 64 + c] = v.w;
    }
    __syncthreads();

    #pragma unroll 2
    for (int kq = 0; kq < 8; ++kq) {
      float4 xr[8];
      #pragma unroll
      for (int i = 0; i < 8; ++i)
        xr[i] = *(const float4*)&xs[(tr * 8 + i) * 32 + ((kq ^ (tr & 7)) << 2)];
      #pragma unroll
      for (int kk = 0; kk < 4; ++kk) {
        int k = kq * 4 + kk;
        float4 w0 = *(const float4*)&wt[k * 64 + c0];
        float4 w1 = *(const float4*)&wt[k * 64 + c0 + 4];
        #pragma unroll
        for (int i = 0; i < 8; ++i) {
          float xv = ((const float*)&xr[i])[kk];
          acc[i][0].x = fmaf(xv, w0.x, acc[i][0].x);
          acc[i][0].y = fmaf(xv, w0.y, acc[i][0].y);
          acc[i][0].z = fmaf(xv, w0.z, acc[i][0].z);
          acc[i][0].w = fmaf(xv, w0.w, acc[i][0].w);
          acc[i][1].x = fmaf(xv, w1.x, acc[i][1].x);
          acc[i][1].y = fmaf(xv, w1.y, acc[i][1].y);
          acc[i][1].z = fmaf(xv, w1.z, acc[i][1].z);
          acc[i][1].w = fmaf(xv, w1.w, acc[i][1].w);
        }
      }
    }
  }

  #pragma unroll
  for (int i = 0; i < 8; ++i) {
    int row = row0 + tr * 8 + i;
    if (row >= N) continue;
    if (MREAL >= 64 || c0 + 7 < MREAL) {
      float dr = dis[row];
      __half hv[8];
      const float* a = (const float*)&acc[i][0];
      #pragma unroll
      for (int j = 0; j < 8; ++j) hv[j] = __float2half_rn(a[j] * dr);
      *(float4*)&Y[(size_t)row * MREAL + c0] = *(float4*)hv;
    }
  }
}

// ---- conv1 (D=64): half-wave per edge slot, 16 edges in flight per wave ----
__launch_bounds__(256)
__global__ void k_conv64(const __half* __restrict__ H, const int* __restrict__ rowptr,
                         const int* __restrict__ srcs, const float* __restrict__ dis,
                         const float* __restrict__ bias, __half* __restrict__ out, int N) {
  int node = blockIdx.x * 4 + (threadIdx.x >> 6);
  if (node >= N) return;                 // wave-uniform
  int lane = threadIdx.x & 63;
  int sub = lane & 31, hf = lane >> 5;
  int s = rowptr[node], e = rowptr[node + 1];
  float ax = 0.f, ay = 0.f;
  int p = s + hf;
  for (; p + 14 < e; p += 16) {          // 8 edges per half-wave in flight
    int si[8];
    #pragma unroll
    for (int u = 0; u < 8; ++u) si[u] = srcs[p + 2 * u];
    #pragma unroll
    for (int u = 0; u < 8; ++u) {
      float2 f = __half22float2(*(const __half2*)&H[(size_t)si[u] * 64 + 2 * sub]);
      ax += f.x; ay += f.y;
    }
  }
  for (; p < e; p += 2) {
    float2 f = __half22float2(*(const __half2*)&H[(size_t)srcs[p] * 64 + 2 * sub]);
    ax += f.x; ay += f.y;
  }
  ax += __shfl_xor(ax, 32);
  ay += __shfl_xor(ay, 32);
  if (hf == 0) {
    float dn = dis[node];
    float vx = fmaxf(fmaf(ax, dn, bias[2 * sub]), 0.f);
    float vy = fmaxf(fmaf(ay, dn, bias[2 * sub + 1]), 0.f);
    *(__half2*)&out[(size_t)node * 64 + 2 * sub] = __floats2half2_rn(vx, vy);
  }
}

// ---- conv2 (D=40, fp32 out): half-wave per edge slot, 16 edges in flight ----
__launch_bounds__(256)
__global__ void k_conv40(const __half* __restrict__ H, const int* __restrict__ rowptr,
                         const int* __restrict__ srcs, const float* __restrict__ dis,
                         const float* __restrict__ bias, float* __restrict__ out, int N) {
  int node = blockIdx.x * 4 + (threadIdx.x >> 6);
  if (node >= N) return;
  int lane = threadIdx.x & 63;
  int sub = lane & 31, hf = lane >> 5;
  bool act = sub < 20;                   // 20 half2 lanes cover 40 features
  int s = rowptr[node], e = rowptr[node + 1];
  float ax = 0.f, ay = 0.f;
  int p = s + hf;
  for (; p + 14 < e; p += 16) {
    int si[8];
    #pragma unroll
    for (int u = 0; u < 8; ++u) si[u] = srcs[p + 2 * u];
    #pragma unroll
    for (int u = 0; u < 8; ++u) {
      float2 f = act ? __half22float2(*(const __half2*)&H[(size_t)si[u] * 40 + 2 * sub])
                     : make_float2(0.f, 0.f);
      ax += f.x; ay += f.y;
    }
  }
  for (; p < e; p += 2) {
    if (act) {
      float2 f = __half22float2(*(const __half2*)&H[(size_t)srcs[p] * 40 + 2 * sub]);
      ax += f.x; ay += f.y;
    }
  }
  ax += __shfl_xor(ax, 32);
  ay += __shfl_xor(ay, 32);
  if (hf == 0 && act) {
    float dn = dis[node];
    float2 v = make_float2(fmaf(ax, dn, bias[2 * sub]), fmaf(ay, dn, bias[2 * sub + 1]));
    *(float2*)&out[(size_t)node * 40 + 2 * sub] = v;
  }
}

extern "C" void kernel_launch(void* const* d_in, const int* in_sizes, int n_in,
                              void* d_out, int out_size, void* d_ws, size_t ws_size,
                              hipStream_t stream) {
  const float* x  = (const float*)d_in[0];
  const int*   ed = (const int*)d_in[1];
  const float* W1 = (const float*)d_in[2];
  const float* b1 = (const float*)d_in[3];
  const float* W2 = (const float*)d_in[4];
  const float* b2 = (const float*)d_in[5];
  float* out = (float*)d_out;

  const int FIN = 128, FH = 64, FO = 40;
  const int N = in_sizes[0] / FIN;
  const int E = in_sizes[1] / 2;
  const int NBINS = (N + 255) >> 8;              // 391

  char* ws = (char*)d_ws;
  size_t off = 0;
  auto alloc = [&](size_t bytes) {
    void* p = ws + off;
    off = (off + bytes + 255) & ~(size_t)255;
    return p;
  };
  int*    flag    = (int*)alloc(4);
  int*    gbincnt = (int*)alloc(512 * 4);
  int*    gbase   = (int*)alloc(512 * 4);
  float*  dis     = (float*)alloc((size_t)N * 4);
  int*    rowptr  = (int*)alloc(((size_t)N + 1) * 4);
  int*    srcs    = (int*)alloc((size_t)E * 4);
  __half* h1      = (__half*)alloc((size_t)N * FH * 2);   // gemm1 out; aliases binbuf
  __half* h1b     = (__half*)alloc((size_t)N * FH * 2);   // conv1 out
  __half* h2      = h1;                                   // gemm2 out reuses h1
  // binbuf aliases h1 (dead before gemm1 writes h1; same-stream ordering)
  int cap = (int)(((size_t)N * FH * 2) / ((size_t)NBINS * 4));
  if (cap > 8192) cap = 8192;                    // mean bin load ~4092
  unsigned* binbuf = (unsigned*)h1;

  hipMemsetAsync(gbincnt, 0, 512 * 4, stream);
  k_detect<<<1, 256, 0, stream>>>(ed, flag, in_sizes[1]);

  int fb = (E + 8191) / 8192;
  k_binfill<<<fb, 256, 0, stream>>>(ed, flag, gbincnt, binbuf, E, cap);
  k_binscan<<<1, 256, 0, stream>>>(gbincnt, gbase, rowptr, NBINS, N, cap);
  k_degscat<<<NBINS, 256, 0, stream>>>(binbuf, gbincnt, gbase, dis, rowptr, srcs, N, cap);

  int mb = (N + 127) / 128;
  int cb = (N + 3) / 4;
  k_gemm1_mfma<<<mb, 256, 0, stream>>>(x, W1, dis, h1, N);
  k_conv64<<<cb, 256, 0, stream>>>(h1, rowptr, srcs, dis, b1, h1b, N);
  k_gemm<64, 40><<<mb, 128, 0, stream>>>(h1b, W2, dis, h2, N);
  k_conv40<<<cb, 256, 0, stream>>>(h2, rowptr, srcs, dis, b2, out, N);
}

// Round 7
// 307.305 us; speedup vs baseline: 4.3054x; 1.0799x over previous
//
#include <hip/hip_runtime.h>
#include <hip/hip_fp16.h>

// ---------------------------------------------------------------------------
// ReconGNN: out = conv(relu(conv(x@W1^T)+b1) @ W2^T) + b2
// R7: R6's batch-16 conv loop only ran once at mean degree 16 and its tail
// had 1 load in flight (conv40 regressed 67->80us). Convs now use a single
// predicated batch-8 loop per half-wave: indices clamped to e-1, accumulate
// masked -> always 8 loads deep, no tail, degree-0 safe.
// Pipeline: memset -> detect -> binfill -> binscan -> degscat ->
//           gemm1_mfma(fp32 in, fp16*dis out) -> conv64(relu+b1) ->
//           gemm2 VALU(fp16 in, fp16*dis out) -> conv40(+b2, fp32 out)
// Aliases: binbuf==h1 (dead before gemm1), h2==h1 (dead after conv1).
// ---------------------------------------------------------------------------

typedef __attribute__((ext_vector_type(8))) _Float16 half8v;
typedef __attribute__((ext_vector_type(4))) float   float4v;

// ---- edge dtype detection: int64 edges read as int32 have all-zero odd words
__global__ void k_detect(const int* __restrict__ ed, int* __restrict__ flag, int nwords) {
  __shared__ int any;
  if (threadIdx.x == 0) any = 0;
  __syncthreads();
  #pragma unroll
  for (int u = 0; u < 8; ++u) {
    int idx = 2 * (threadIdx.x * 8 + u) + 1;
    if (idx < nwords && ed[idx] != 0) any = 1;
  }
  __syncthreads();
  if (threadIdx.x == 0) *flag = any ? 0 : 1;   // 1 => int64 layout
}

// ---- bucket edges by destination bin (c>>8), coalesced run writes ----
// record = r | (c&255)<<17   (N <= 131072)
__global__ void k_binfill(const int* __restrict__ ed, const int* __restrict__ flag,
                          int* __restrict__ gbincnt, unsigned* __restrict__ binbuf,
                          int E, int cap) {
  __shared__ int hist[512];
  __shared__ int cursor[512];
  int t = threadIdx.x;
  hist[t] = 0; hist[t + 256] = 0;
  __syncthreads();
  const int is64 = *flag;
  const int base = blockIdx.x * 8192;
  const int nE = min(8192, E - base);
  for (int j = t; j < nE; j += 256) {
    int e = base + j;
    int c = is64 ? ed[2 * (E + e)] : ed[E + e];
    atomicAdd(&hist[c >> 8], 1);
  }
  __syncthreads();
  for (int b = t; b < 512; b += 256) {
    int h = hist[b];
    cursor[b] = h ? atomicAdd(&gbincnt[b], h) : 0;
  }
  __syncthreads();
  for (int j = t; j < nE; j += 256) {
    int e = base + j;
    int r = is64 ? ed[2 * e] : ed[e];
    int c = is64 ? ed[2 * (E + e)] : ed[E + e];
    int bin = c >> 8;
    int pos = atomicAdd(&cursor[bin], 1);
    if (pos < cap)
      binbuf[(size_t)bin * cap + pos] = (unsigned)r | ((unsigned)(c & 255) << 17);
  }
}

// ---- single-block exclusive scan over clamped bin counts -> gbase ----
__global__ void k_binscan(const int* __restrict__ gbincnt, int* __restrict__ gbase,
                          int* __restrict__ rowptr, int NBINS, int N, int cap) {
  __shared__ int sd[512];
  int t = threadIdx.x;
  #pragma unroll
  for (int u = 0; u < 2; ++u) {
    int i = t + 256 * u;
    sd[i] = (i < NBINS) ? min(gbincnt[i], cap) : 0;
  }
  __syncthreads();
  for (int off = 1; off < 512; off <<= 1) {
    int v0 = (t >= off) ? sd[t - off] : 0;
    int i1 = t + 256;
    int v1 = sd[i1 - off];
    __syncthreads();
    sd[t] += v0; sd[i1] += v1;
    __syncthreads();
  }
  #pragma unroll
  for (int u = 0; u < 2; ++u) {
    int i = t + 256 * u;
    if (i < NBINS) gbase[i] = (i == 0) ? 0 : sd[i - 1];
  }
  if (t == 0) rowptr[N] = sd[NBINS - 1];
}

// ---- fused: per-bin degree + scan -> dis/rowptr, then scatter srcs ----
__global__ void k_degscat(const unsigned* __restrict__ binbuf, const int* __restrict__ gbincnt,
                          const int* __restrict__ gbase, float* __restrict__ dis,
                          int* __restrict__ rowptr, int* __restrict__ srcs, int N, int cap) {
  __shared__ int cnt[256];
  __shared__ int sd[256];
  __shared__ int cursor[256];
  int t = threadIdx.x, b = blockIdx.x;
  cnt[t] = 0;
  __syncthreads();
  int n = min(gbincnt[b], cap);
  const unsigned* buf = binbuf + (size_t)b * cap;
  for (int j = t; j < n; j += 256) atomicAdd(&cnt[buf[j] >> 17], 1);
  __syncthreads();
  sd[t] = cnt[t];
  __syncthreads();
  for (int off = 1; off < 256; off <<= 1) {
    int v = (t >= off) ? sd[t - off] : 0;
    __syncthreads();
    sd[t] += v;
    __syncthreads();
  }
  int rp = gbase[b] + ((t == 0) ? 0 : sd[t - 1]);
  cursor[t] = rp;
  int node = b * 256 + t;
  if (node < N) {
    int d = cnt[t];
    dis[node] = (d > 0) ? rsqrtf((float)d) : 0.f;
    rowptr[node] = rp;
  }
  __syncthreads();
  for (int j = t; j < n; j += 256) {
    unsigned rec = buf[j];
    int pos = atomicAdd(&cursor[rec >> 17], 1);
    srcs[pos] = (int)(rec & 0x1FFFF);
  }
}

// ---- gemm1 (MFMA f16): Y[N][64] = (X[N][128] @ W[64][128]^T) * dis, fp16 out
__launch_bounds__(256)
__global__ void k_gemm1_mfma(const float* __restrict__ X, const float* __restrict__ W,
                             const float* __restrict__ dis, __half* __restrict__ Y, int N) {
  __shared__ _Float16 xl[128 * 128];   // 32 KB
  __shared__ _Float16 wl[64 * 128];    // 16 KB
  const int t = threadIdx.x;
  const int row0 = blockIdx.x * 128;

  {
    int n = t >> 2, kb = (t & 3) * 32;
    const float* src = W + n * 128 + kb;
    #pragma unroll
    for (int j = 0; j < 4; ++j) {
      float4 va = *(const float4*)&src[j * 8];
      float4 vb = *(const float4*)&src[j * 8 + 4];
      _Float16 h8[8] = {(_Float16)va.x, (_Float16)va.y, (_Float16)va.z, (_Float16)va.w,
                        (_Float16)vb.x, (_Float16)vb.y, (_Float16)vb.z, (_Float16)vb.w};
      int k = kb + j * 8;
      *(float4*)&wl[n * 128 + (k ^ ((n & 7) * 8))] = *(float4*)h8;
    }
  }
  {
    int r = t >> 1, kb = (t & 1) * 64;
    int row = row0 + r;
    #pragma unroll
    for (int j = 0; j < 8; ++j) {
      float4 va = make_float4(0.f, 0.f, 0.f, 0.f), vb = va;
      if (row < N) {
        va = *(const float4*)&X[(size_t)row * 128 + kb + j * 8];
        vb = *(const float4*)&X[(size_t)row * 128 + kb + j * 8 + 4];
      }
      _Float16 h8[8] = {(_Float16)va.x, (_Float16)va.y, (_Float16)va.z, (_Float16)va.w,
                        (_Float16)vb.x, (_Float16)vb.y, (_Float16)vb.z, (_Float16)vb.w};
      int k = kb + j * 8;
      *(float4*)&xl[r * 128 + (k ^ ((r & 7) * 8))] = *(float4*)h8;
    }
  }
  __syncthreads();

  const int w = t >> 6, l = t & 63;
  const int m0 = w * 32;
  const int lr = l & 15, q = l >> 4;

  float4v acc[2][4] = {};
  #pragma unroll
  for (int kc = 0; kc < 4; ++kc) {
    half8v a[2], b[4];
    #pragma unroll
    for (int mt = 0; mt < 2; ++mt) {
      int m = m0 + mt * 16 + lr;
      int k = (kc * 32 + q * 8) ^ ((m & 7) * 8);
      a[mt] = *(half8v*)&xl[m * 128 + k];
    }
    #pragma unroll
    for (int nt = 0; nt < 4; ++nt) {
      int n = nt * 16 + lr;
      int k = (kc * 32 + q * 8) ^ ((n & 7) * 8);
      b[nt] = *(half8v*)&wl[n * 128 + k];
    }
    #pragma unroll
    for (int mt = 0; mt < 2; ++mt)
      #pragma unroll
      for (int nt = 0; nt < 4; ++nt)
        acc[mt][nt] = __builtin_amdgcn_mfma_f32_16x16x32_f16(a[mt], b[nt], acc[mt][nt], 0, 0, 0);
  }

  #pragma unroll
  for (int mt = 0; mt < 2; ++mt) {
    #pragma unroll
    for (int r = 0; r < 4; ++r) {
      int row = row0 + m0 + mt * 16 + q * 4 + r;
      if (row < N) {
        float dr = dis[row];
        #pragma unroll
        for (int nt = 0; nt < 4; ++nt)
          Y[(size_t)row * 64 + nt * 16 + lr] = __float2half_rn(acc[mt][nt][r] * dr);
      }
    }
  }
}

// ---- GEMM (VALU, gemm2): Y = (X @ W^T) * dis, fp16 in/out ----
template<int KFULL, int MREAL>
__launch_bounds__(128)
__global__ void k_gemm(const __half* __restrict__ Xh, const float* __restrict__ W,
                       const float* __restrict__ dis, __half* __restrict__ Y, int N) {
  constexpr int BM = 128, BK = 32;
  __shared__ float xs[BM * BK];
  __shared__ float wt[BK * 64];
  const int tid = threadIdx.x;
  const int tr = tid >> 3;
  const int tc = tid & 7;
  const int row0 = blockIdx.x * BM;
  const int c0 = tc * 8;

  float4 acc[8][2];
  #pragma unroll
  for (int i = 0; i < 8; ++i) {
    acc[i][0] = make_float4(0.f, 0.f, 0.f, 0.f);
    acc[i][1] = make_float4(0.f, 0.f, 0.f, 0.f);
  }

  #pragma unroll 1
  for (int kt = 0; kt < KFULL / BK; ++kt) {
    if (kt) __syncthreads();
    #pragma unroll
    for (int j = 0; j < 8; ++j) {
      int q = tid + 128 * j;
      int r = q >> 3, kq = q & 7;
      float4 v = make_float4(0.f, 0.f, 0.f, 0.f);
      int row = row0 + r;
      if (row < N) {
        float2 raw = *(const float2*)&Xh[(size_t)row * KFULL + kt * BK + kq * 4];
        const __half* hp = (const __half*)&raw;
        v = make_float4(__half2float(hp[0]), __half2float(hp[1]),
                        __half2float(hp[2]), __half2float(hp[3]));
      }
      *(float4*)&xs[r * 32 + ((kq ^ ((r >> 3) & 7)) << 2)] = v;
    }
    #pragma unroll
    for (int j = 0; j < 4; ++j) {
      int q = tid + 128 * j;
      int c = q >> 3, kq = q & 7;
      float4 v = make_float4(0.f, 0.f, 0.f, 0.f);
      if (c < MREAL) v = *(const float4*)&W[(size_t)c * KFULL + kt * BK + kq * 4];
      wt[(kq * 4 + 0) * 64 + c] = v.x;
      wt[(kq * 4 + 1) * 64 + c] = v.y;
      wt[(kq * 4 + 2) * 64 + c] = v.z;
      wt[(kq * 4 + 3) * 64 + c] = v.w;
    }
    __syncthreads();

    #pragma unroll 2
    for (int kq = 0; kq < 8; ++kq) {
      float4 xr[8];
      #pragma unroll
      for (int i = 0; i < 8; ++i)
        xr[i] = *(const float4*)&xs[(tr * 8 + i) * 32 + ((kq ^ (tr & 7)) << 2)];
      #pragma unroll
      for (int kk = 0; kk < 4; ++kk) {
        int k = kq * 4 + kk;
        float4 w0 = *(const float4*)&wt[k * 64 + c0];
        float4 w1 = *(const float4*)&wt[k * 64 + c0 + 4];
        #pragma unroll
        for (int i = 0; i < 8; ++i) {
          float xv = ((const float*)&xr[i])[kk];
          acc[i][0].x = fmaf(xv, w0.x, acc[i][0].x);
          acc[i][0].y = fmaf(xv, w0.y, acc[i][0].y);
          acc[i][0].z = fmaf(xv, w0.z, acc[i][0].z);
          acc[i][0].w = fmaf(xv, w0.w, acc[i][0].w);
          acc[i][1].x = fmaf(xv, w1.x, acc[i][1].x);
          acc[i][1].y = fmaf(xv, w1.y, acc[i][1].y);
          acc[i][1].z = fmaf(xv, w1.z, acc[i][1].z);
          acc[i][1].w = fmaf(xv, w1.w, acc[i][1].w);
        }
      }
    }
  }

  #pragma unroll
  for (int i = 0; i < 8; ++i) {
    int row = row0 + tr * 8 + i;
    if (row >= N) continue;
    if (MREAL >= 64 || c0 + 7 < MREAL) {
      float dr = dis[row];
      __half hv[8];
      const float* a = (const float*)&acc[i][0];
      #pragma unroll
      for (int j = 0; j < 8; ++j) hv[j] = __float2half_rn(a[j] * dr);
      *(float4*)&Y[(size_t)row * MREAL + c0] = *(float4*)hv;
    }
  }
}

// ---- conv1 (D=64): predicated batch-8 per half-wave, always 8 loads deep ----
__launch_bounds__(256)
__global__ void k_conv64(const __half* __restrict__ H, const int* __restrict__ rowptr,
                         const int* __restrict__ srcs, const float* __restrict__ dis,
                         const float* __restrict__ bias, __half* __restrict__ out, int N) {
  int node = blockIdx.x * 4 + (threadIdx.x >> 6);
  if (node >= N) return;                 // wave-uniform
  int lane = threadIdx.x & 63;
  int sub = lane & 31, hf = lane >> 5;
  int s = rowptr[node], e = rowptr[node + 1];
  int last = e - 1;
  float ax = 0.f, ay = 0.f;
  for (int p = s + hf; p < e; p += 16) { // loop skipped entirely if deg==0
    int si[8];
    #pragma unroll
    for (int u = 0; u < 8; ++u) si[u] = srcs[min(p + 2 * u, last)];
    #pragma unroll
    for (int u = 0; u < 8; ++u) {
      float2 f = __half22float2(*(const __half2*)&H[(size_t)si[u] * 64 + 2 * sub]);
      if (p + 2 * u < e) { ax += f.x; ay += f.y; }
    }
  }
  ax += __shfl_xor(ax, 32);
  ay += __shfl_xor(ay, 32);
  if (hf == 0) {
    float dn = dis[node];
    float vx = fmaxf(fmaf(ax, dn, bias[2 * sub]), 0.f);
    float vy = fmaxf(fmaf(ay, dn, bias[2 * sub + 1]), 0.f);
    *(__half2*)&out[(size_t)node * 64 + 2 * sub] = __floats2half2_rn(vx, vy);
  }
}

// ---- conv2 (D=40, fp32 out): predicated batch-8 per half-wave ----
__launch_bounds__(256)
__global__ void k_conv40(const __half* __restrict__ H, const int* __restrict__ rowptr,
                         const int* __restrict__ srcs, const float* __restrict__ dis,
                         const float* __restrict__ bias, float* __restrict__ out, int N) {
  int node = blockIdx.x * 4 + (threadIdx.x >> 6);
  if (node >= N) return;
  int lane = threadIdx.x & 63;
  int sub = lane & 31, hf = lane >> 5;
  bool act = sub < 20;                   // 20 half2 lanes cover 40 features
  int s = rowptr[node], e = rowptr[node + 1];
  int last = e - 1;
  float ax = 0.f, ay = 0.f;
  for (int p = s + hf; p < e; p += 16) {
    int si[8];
    #pragma unroll
    for (int u = 0; u < 8; ++u) si[u] = srcs[min(p + 2 * u, last)];
    #pragma unroll
    for (int u = 0; u < 8; ++u) {
      if (act) {
        float2 f = __half22float2(*(const __half2*)&H[(size_t)si[u] * 40 + 2 * sub]);
        if (p + 2 * u < e) { ax += f.x; ay += f.y; }
      }
    }
  }
  ax += __shfl_xor(ax, 32);
  ay += __shfl_xor(ay, 32);
  if (hf == 0 && act) {
    float dn = dis[node];
    float2 v = make_float2(fmaf(ax, dn, bias[2 * sub]), fmaf(ay, dn, bias[2 * sub + 1]));
    *(float2*)&out[(size_t)node * 40 + 2 * sub] = v;
  }
}

extern "C" void kernel_launch(void* const* d_in, const int* in_sizes, int n_in,
                              void* d_out, int out_size, void* d_ws, size_t ws_size,
                              hipStream_t stream) {
  const float* x  = (const float*)d_in[0];
  const int*   ed = (const int*)d_in[1];
  const float* W1 = (const float*)d_in[2];
  const float* b1 = (const float*)d_in[3];
  const float* W2 = (const float*)d_in[4];
  const float* b2 = (const float*)d_in[5];
  float* out = (float*)d_out;

  const int FIN = 128, FH = 64, FO = 40;
  const int N = in_sizes[0] / FIN;
  const int E = in_sizes[1] / 2;
  const int NBINS = (N + 255) >> 8;              // 391

  char* ws = (char*)d_ws;
  size_t off = 0;
  auto alloc = [&](size_t bytes) {
    void* p = ws + off;
    off = (off + bytes + 255) & ~(size_t)255;
    return p;
  };
  int*    flag    = (int*)alloc(4);
  int*    gbincnt = (int*)alloc(512 * 4);
  int*    gbase   = (int*)alloc(512 * 4);
  float*  dis     = (float*)alloc((size_t)N * 4);
  int*    rowptr  = (int*)alloc(((size_t)N + 1) * 4);
  int*    srcs    = (int*)alloc((size_t)E * 4);
  __half* h1      = (__half*)alloc((size_t)N * FH * 2);   // gemm1 out; aliases binbuf
  __half* h1b     = (__half*)alloc((size_t)N * FH * 2);   // conv1 out
  __half* h2      = h1;                                   // gemm2 out reuses h1
  int cap = (int)(((size_t)N * FH * 2) / ((size_t)NBINS * 4));
  if (cap > 8192) cap = 8192;                    // mean bin load ~4092
  unsigned* binbuf = (unsigned*)h1;

  hipMemsetAsync(gbincnt, 0, 512 * 4, stream);
  k_detect<<<1, 256, 0, stream>>>(ed, flag, in_sizes[1]);

  int fb = (E + 8191) / 8192;
  k_binfill<<<fb, 256, 0, stream>>>(ed, flag, gbincnt, binbuf, E, cap);
  k_binscan<<<1, 256, 0, stream>>>(gbincnt, gbase, rowptr, NBINS, N, cap);
  k_degscat<<<NBINS, 256, 0, stream>>>(binbuf, gbincnt, gbase, dis, rowptr, srcs, N, cap);

  int mb = (N + 127) / 128;
  int cb = (N + 3) / 4;
  k_gemm1_mfma<<<mb, 256, 0, stream>>>(x, W1, dis, h1, N);
  k_conv64<<<cb, 256, 0, stream>>>(h1, rowptr, srcs, dis, b1, h1b, N);
  k_gemm<64, 40><<<mb, 128, 0, stream>>>(h1b, W2, dis, h2, N);
  k_conv40<<<cb, 256, 0, stream>>>(h2, rowptr, srcs, dis, b2, out, N);
}